// Round 17
// baseline (178.367 us; speedup 1.0000x reference)
//
#include <hip/hip_runtime.h>
#include <hip/hip_bf16.h>
#include <stdint.h>

// Problem constants
#define B_   8
#define S_   2048
#define D_   1280
#define OUT_ 1280
#define K_   (2 * D_)     // 2560
#define M_   (B_ * S_)    // 16384

// GEMM geometry: 128x256 tile, BK=32, 4 waves of 128x64, grid 640 (2 blk/CU)
#define BM    128
#define BN    256
#define BK    32
#define NKT   (K_ / BK)        // 80
#define AT_E  (BM * BK)        // 4096 elems (8 KB) per A K-tile
#define BT_E  (BN * BK)        // 8192 elems (16 KB) per B K-tile
#define BUF_E (AT_E + BT_E)    // 12288 elems = 24 KB per LDS buffer (x3 = 72 KB)
#define NMT   (M_ / BM)        // 128
#define NNT   (OUT_ / BN)      // 5

typedef __bf16 bf16_t;
typedef bf16_t bf16x8 __attribute__((ext_vector_type(8)));
typedef float  f32x4  __attribute__((ext_vector_type(4)));

// ---------------------------------------------------------------------------
// lengths: per-batch valid count (prefix mask). Handles byte or int32 storage.
// ---------------------------------------------------------------------------
__global__ void lengths_kernel(const unsigned char* __restrict__ mask,
                               int* __restrict__ len) {
    const int b = blockIdx.x;
    const bool bytefmt = (mask[1] != 0);   // lengths >= 512 so elem 1 is true
    int cnt = 0;
    if (bytefmt) {
        for (int s = threadIdx.x; s < S_; s += blockDim.x)
            cnt += (mask[(size_t)b * S_ + s] != 0) ? 1 : 0;
    } else {
        const int* mi = (const int*)mask;
        for (int s = threadIdx.x; s < S_; s += blockDim.x)
            cnt += (mi[(size_t)b * S_ + s] != 0) ? 1 : 0;
    }
    #pragma unroll
    for (int off = 32; off > 0; off >>= 1) cnt += __shfl_down(cnt, off);
    __shared__ int wsum[4];
    const int wid = threadIdx.x >> 6;
    if ((threadIdx.x & 63) == 0) wsum[wid] = cnt;
    __syncthreads();
    if (threadIdx.x == 0) len[b] = wsum[0] + wsum[1] + wsum[2] + wsum[3];
}

__device__ inline bf16x8 cvt8(float4 x, float4 y) {
    bf16x8 r;
    r[0] = (bf16_t)x.x; r[1] = (bf16_t)x.y; r[2] = (bf16_t)x.z; r[3] = (bf16_t)x.w;
    r[4] = (bf16_t)y.x; r[5] = (bf16_t)y.y; r[6] = (bf16_t)y.z; r[7] = (bf16_t)y.w;
    return r;
}

// Pack W (coalesced): [5 nt][80 kt][256r x 32k] tiles; chunk c of row r at
// slot (c ^ ((r>>1)&3)), elem offset r*32 + slot*8.
__global__ __launch_bounds__(256) void pack_w6_kernel(
    const float* __restrict__ W, bf16_t* __restrict__ packW) {
    const int kt = blockIdx.x;            // 0..79
    const int nt = blockIdx.y;            // 0..4
    const int c  = threadIdx.x & 3;
    const int r0 = threadIdx.x >> 2;      // 0..63
    const int kk = kt * BK + c * 8;
    bf16_t* dst = packW + ((size_t)nt * NKT + kt) * BT_E;
    #pragma unroll
    for (int p = 0; p < 4; ++p) {
        const int r = r0 + p * 64;        // 0..255
        const float* src = W + (size_t)(nt * BN + r) * K_ + kk;
        float4 x = *(const float4*)src;
        float4 y = *(const float4*)(src + 4);
        const int slot = c ^ ((r >> 1) & 3);
        *(bf16x8*)(dst + r * BK + slot * 8) = cvt8(x, y);
    }
}

// ---------------------------------------------------------------------------
// Fused GEMM gemm18: gemm13's schedule VERBATIM (top-issue A->nx, COMPUTE,
// write-late cvt+GLL, cu<-nx — the proven family optimum), with BM halved so
// TWO blocks co-reside per CU in independent barrier domains. Unlike R15,
// each thread still owns ONE A-row (4+4 staging float4, same as gemm13) so
// register pressure is unchanged -> no spill. When one block stalls on its
// counted wait, the other block's waves fill the MFMA/LDS pipes.
// Per-iter vmem queue: [B(kt):4, A(kt+2):4, B(kt+1):4] -> uniform vmcnt(8).
// ---------------------------------------------------------------------------
#define GLL(gp, lp) __builtin_amdgcn_global_load_lds(                        \
    (const __attribute__((address_space(1))) unsigned int*)(const void*)(gp),\
    (__attribute__((address_space(3))) unsigned int*)(void*)(lp), 16, 0, 0)

#define BOUNDARY_U(N)                                                        \
    asm volatile("s_waitcnt lgkmcnt(0)" ::: "memory");                       \
    asm volatile("s_waitcnt vmcnt(" #N ")" ::: "memory");                    \
    __builtin_amdgcn_s_barrier();                                            \
    __builtin_amdgcn_sched_barrier(0);

#define COMPUTE_TILE(OFF)                                                    \
    { bf16x8 af[8], bfr[4];                                                  \
      _Pragma("unroll") for (int i = 0; i < 8; ++i)                          \
          af[i] = *(const bf16x8*)&lds[(OFF) + aoff + i * 512];              \
      _Pragma("unroll") for (int j = 0; j < 4; ++j)                          \
          bfr[j] = *(const bf16x8*)&lds[(OFF) + boff + j * 512];             \
      __builtin_amdgcn_s_setprio(1);                                         \
      _Pragma("unroll") for (int i = 0; i < 8; ++i)                          \
          _Pragma("unroll") for (int j = 0; j < 4; ++j)                      \
              acc[i][j] = __builtin_amdgcn_mfma_f32_16x16x32_bf16(           \
                  af[i], bfr[j], acc[i][j], 0, 0, 0);                        \
      __builtin_amdgcn_s_setprio(0);                                         \
      __builtin_amdgcn_sched_barrier(0); }

#define GLL_B4(KT, OFF)                                                      \
    { const bf16_t* btile = gB + (size_t)(KT) * BT_E;                        \
      GLL(btile + (w +  0) * 512 + l8, &lds[(OFF) + AT_E + (w +  0) * 512]); \
      GLL(btile + (w +  4) * 512 + l8, &lds[(OFF) + AT_E + (w +  4) * 512]); \
      GLL(btile + (w +  8) * 512 + l8, &lds[(OFF) + AT_E + (w +  8) * 512]); \
      GLL(btile + (w + 12) * 512 + l8, &lds[(OFF) + AT_E + (w + 12) * 512]); }

__global__ __launch_bounds__(256, 2) void gemm18_kernel(
    const float* __restrict__ fwd, const float* __restrict__ rev,
    const bf16_t* __restrict__ pW, const int* __restrict__ len,
    const float* __restrict__ bias, float* __restrict__ out) {

    __shared__ __align__(16) bf16_t lds[3 * BUF_E];   // 73728 B -> 2 blk/CU

    // XCD swizzle (bijective: 640 = 8 x 80): XCD x gets 80 consecutive swz =
    // 16 rt-panels x 5 cts -> A re-read (5x) stays within one XCD's L2.
    const int bid = blockIdx.x;
    const int swz = (bid & 7) * 80 + (bid >> 3);
    const int rt  = swz / NNT;            // 0..127
    const int ct  = swz % NNT;            // 0..4

    const int t  = threadIdx.x;
    const int l  = t & 63;
    const int w  = t >> 6;                // 0..3
    const int wn = w;                     // 64-col group

    const bf16_t* gB = pW + (size_t)ct * NKT * BT_E;
    const int l8 = l * 8;

    // ---- A gather: thread t owns row r = t>>1, k-half kh = (t&1)*16 ----
    const int r  = t >> 1;                // 0..127
    const int kh = (t & 1) * 16;
    const int m  = rt * BM + r;
    const int b  = m >> 11;
    const int s  = m & (S_ - 1);
    const int n  = len[b];
    const int ss = (s < n) ? (n - 1 - s) : s;
    const float* pf = fwd + (size_t)(b * S_ + s)  * D_;        // + kk (k < D)
    const float* pr = rev + (size_t)(b * S_ + ss) * D_ - D_;   // + kk (k >= D)
    const int swr = (r >> 1) & 3;
    const int wo0 = r * BK + (((kh >> 3) + 0) ^ swr) * 8;
    const int wo1 = r * BK + (((kh >> 3) + 1) ^ swr) * 8;

    // fragment read offsets (round-5-verified swizzle)
    const int lrow = l & 15;
    const int slot = (l >> 4) ^ ((lrow >> 1) & 3);
    const int aoff = lrow * BK + slot * 8;                     // rows i*16+lrow
    const int boff = AT_E + (wn * 64 + lrow) * BK + slot * 8;  // cols j*16+lrow

    f32x4 acc[8][4] = {};
    float4 cu0, cu1, cu2, cu3, nx0, nx1, nx2, nx3;

    // ---- prologue (issue order matches steady state: B(0), A(2), B(1)) ----
    #pragma unroll
    for (int p = 0; p < 2; ++p) {         // A(0)->buf0, A(1)->buf1 (drained)
        const float* sp = pf + p * BK + kh;
        float4 x0 = *(const float4*)(sp);
        float4 x1 = *(const float4*)(sp + 4);
        float4 x2 = *(const float4*)(sp + 8);
        float4 x3 = *(const float4*)(sp + 12);
        bf16_t* dst = &lds[p * BUF_E];
        *(bf16x8*)(dst + wo0) = cvt8(x0, x1);
        *(bf16x8*)(dst + wo1) = cvt8(x2, x3);
    }
    GLL_B4(0, 0)                          // GLL B(0) -> buf0
    {   // issue A(2) -> cu
        const float* sp = pf + 2 * BK + kh;
        cu0 = *(const float4*)(sp);
        cu1 = *(const float4*)(sp + 4);
        cu2 = *(const float4*)(sp + 8);
        cu3 = *(const float4*)(sp + 12);
    }
    GLL_B4(1, BUF_E)                      // GLL B(1) -> buf1

    int o0 = 0, o1 = BUF_E, o2 = 2 * BUF_E;

    // ---- main loop: kt = 0 .. NKT-4 (all issues unconditional) ----
    for (int kt = 0; kt < NKT - 3; ++kt) {
        BOUNDARY_U(8)         // drains B(kt); leaves {A(kt+2):4, B(kt+1):4}

        {   // issue-early: A(kt+3) -> nx (wave-uniform branch; D_ % BK == 0)
            const int kk = (kt + 3) * BK + kh;
            const float* sp = ((kk < D_) ? pf : pr) + kk;
            nx0 = *(const float4*)(sp);
            nx1 = *(const float4*)(sp + 4);
            nx2 = *(const float4*)(sp + 8);
            nx3 = *(const float4*)(sp + 12);
        }
        __builtin_amdgcn_sched_barrier(0);

        COMPUTE_TILE(o0)

        // write-late: cvt cu = A(kt+2) -> o2 (counted wait: leaves B(kt+1)+nx)
        {
            bf16_t* dst = &lds[o2];
            *(bf16x8*)(dst + wo0) = cvt8(cu0, cu1);
            *(bf16x8*)(dst + wo1) = cvt8(cu2, cu3);
        }
        GLL_B4(kt + 2, o2)
        cu0 = nx0; cu1 = nx1; cu2 = nx2; cu3 = nx3;

        const int tmp = o0; o0 = o1; o1 = o2; o2 = tmp;
    }

    // ---- tail kt = NKT-3: steady boundary; write A(NKT-1), GLL B(NKT-1) ----
    {
        BOUNDARY_U(8)
        COMPUTE_TILE(o0)
        bf16_t* dst = &lds[o2];
        *(bf16x8*)(dst + wo0) = cvt8(cu0, cu1);
        *(bf16x8*)(dst + wo1) = cvt8(cu2, cu3);
        GLL_B4(NKT - 1, o2)
        const int tmp = o0; o0 = o1; o1 = o2; o2 = tmp;
    }
    // ---- tail kt = NKT-2: queue = {B(NKT-2):4, B(NKT-1):4} ----
    {
        BOUNDARY_U(4)
        COMPUTE_TILE(o0)
        const int tmp = o0; o0 = o1; o1 = o2; o2 = tmp;
    }
    // ---- tail kt = NKT-1 ----
    {
        BOUNDARY_U(0)
        COMPUTE_TILE(o0)
    }

    // ---- epilogue: C/D layout col=lane&15, row=(lane>>4)*4+v ----
    const int m0 = rt * BM;
    const int n0 = ct * BN + wn * 64;
    const int r4 = (l >> 4) * 4;
    #pragma unroll
    for (int j = 0; j < 4; ++j) {
        const int col = n0 + j * 16 + lrow;
        const float bj = bias[col];
        #pragma unroll
        for (int i = 0; i < 8; ++i) {
            const int row0 = m0 + i * 16 + r4;
            #pragma unroll
            for (int v = 0; v < 4; ++v)
                out[(size_t)(row0 + v) * OUT_ + col] = acc[i][j][v] + bj;
        }
    }
}

// ---------------------------------------------------------------------------
// Fallback (round-1 kernel): used only if ws_size can't hold packed W.
// ---------------------------------------------------------------------------
#define LDKF 40
__global__ __launch_bounds__(256) void profam_gemm_fallback(
    const float* __restrict__ fwd, const float* __restrict__ rev,
    const float* __restrict__ W,   const float* __restrict__ bias,
    const int* __restrict__ len,   float* __restrict__ out) {

    __shared__ __align__(16) bf16_t lds_a[128][LDKF];
    __shared__ __align__(16) bf16_t lds_b[128][LDKF];

    const int ct = blockIdx.x;
    const int rt = blockIdx.y;
    const int m0 = rt * 128;
    const int n0 = ct * 128;
    const int t  = threadIdx.x;
    const int l  = t & 63;
    const int w  = t >> 6;
    const int wr = w >> 1, wc = w & 1;

    const int b = m0 >> 11;
    const int n = len[b];

    const int sr = t >> 1;
    const int cg = (t & 1) * 16;
    const int s  = (m0 + sr) & (S_ - 1);
    const int ss = (s < n) ? (n - 1 - s) : s;
    const float* pf = fwd + (size_t)(b * S_ + s)  * D_ + cg;
    const float* pr = rev + (size_t)(b * S_ + ss) * D_ + cg;
    const float* pw = W   + (size_t)(n0 + sr) * K_ + cg;

    f32x4 acc[4][4] = {};
    const int lrow = l & 15;
    const int kc   = (l >> 4) * 8;

    for (int kt = 0; kt < K_ / 32; ++kt) {
        const int k0 = kt * 32;
        const float* pa = (k0 < D_) ? (pf + k0) : (pr + (k0 - D_));
        const float* pb = pw + k0;
        float4 a0 = *(const float4*)(pa + 0);
        float4 a1 = *(const float4*)(pa + 4);
        float4 a2 = *(const float4*)(pa + 8);
        float4 a3 = *(const float4*)(pa + 12);
        float4 b0 = *(const float4*)(pb + 0);
        float4 b1 = *(const float4*)(pb + 4);
        float4 b2 = *(const float4*)(pb + 8);
        float4 b3 = *(const float4*)(pb + 12);
        *(bf16x8*)&lds_a[sr][cg + 0] = cvt8(a0, a1);
        *(bf16x8*)&lds_a[sr][cg + 8] = cvt8(a2, a3);
        *(bf16x8*)&lds_b[sr][cg + 0] = cvt8(b0, b1);
        *(bf16x8*)&lds_b[sr][cg + 8] = cvt8(b2, b3);
        __syncthreads();
        bf16x8 af[4], bfr[4];
        #pragma unroll
        for (int i = 0; i < 4; ++i)
            af[i] = *(const bf16x8*)&lds_a[wr * 64 + i * 16 + lrow][kc];
        #pragma unroll
        for (int j = 0; j < 4; ++j)
            bfr[j] = *(const bf16x8*)&lds_b[wc * 64 + j * 16 + lrow][kc];
        #pragma unroll
        for (int i = 0; i < 4; ++i)
            #pragma unroll
            for (int j = 0; j < 4; ++j)
                acc[i][j] = __builtin_amdgcn_mfma_f32_16x16x32_bf16(
                    af[i], bfr[j], acc[i][j], 0, 0, 0);
        __syncthreads();
    }
    #pragma unroll
    for (int j = 0; j < 4; ++j) {
        const int col = n0 + wc * 64 + j * 16 + lrow;
        const float bj = bias[col];
        #pragma unroll
        for (int i = 0; i < 4; ++i) {
            const int row0 = m0 + wr * 64 + i * 16 + (l >> 4) * 4;
            #pragma unroll
            for (int v = 0; v < 4; ++v)
                out[(size_t)(row0 + v) * OUT_ + col] = acc[i][j][v] + bj;
        }
    }
}

extern "C" void kernel_launch(void* const* d_in, const int* in_sizes, int n_in,
                              void* d_out, int out_size, void* d_ws, size_t ws_size,
                              hipStream_t stream) {
    const float* fwd  = (const float*)d_in[0];
    const float* rev  = (const float*)d_in[1];
    const unsigned char* mask = (const unsigned char*)d_in[2];
    const float* W    = (const float*)d_in[3];
    const float* bias = (const float*)d_in[4];
    float* out = (float*)d_out;

    int* len = (int*)d_ws;                                    // 8 ints @ offset 0
    const size_t offW = 256;
    const size_t szW  = (size_t)NNT * NKT * BT_E * 2;         // 6.55 MB
    const size_t need = offW + szW;

    lengths_kernel<<<dim3(B_), dim3(256), 0, stream>>>(mask, len);

    if (ws_size >= need) {
        bf16_t* packW = (bf16_t*)((char*)d_ws + offW);
        pack_w6_kernel<<<dim3(NKT, NNT), dim3(256), 0, stream>>>(W, packW);
        gemm18_kernel<<<dim3(NMT * NNT), dim3(256), 0, stream>>>(
            fwd, rev, packW, len, bias, out);
    } else {
        profam_gemm_fallback<<<dim3(OUT_ / 128, M_ / 128), dim3(256), 0, stream>>>(
            fwd, rev, W, bias, len, out);
    }
}